// Round 1
// baseline (4860.563 us; speedup 1.0000x reference)
//
#include <hip/hip_runtime.h>
#include <hip/hip_bf16.h>
#include <math.h>

#define LSEQ 256
#define BB   64
#define EE   256
#define HH   256
#define TT   16

// ---------------- embedding gather: x0[r][e] = emb[tokens[r]][e] ----------------
__global__ __launch_bounds__(64)
void embed_kernel(const int* __restrict__ tokens, const float* __restrict__ emb,
                  float* __restrict__ x0) {
    int r = blockIdx.x;                       // r = t*B + b, 0..16383
    int tok = tokens[r];
    const float4* src = (const float4*)(emb + (size_t)tok * EE);
    float4* dst = (float4*)(x0 + (size_t)r * EE);
    dst[threadIdx.x] = src[threadIdx.x];      // 64 threads * float4 = 256 floats
}

// -------- pack W_hh into Wp[k][j][4] = w_hh[(g*256+j)][k] for coalesced float4 --------
__global__ __launch_bounds__(256)
void pack_whh_kernel(const float* __restrict__ w0, const float* __restrict__ w1,
                     const float* __restrict__ w2, const float* __restrict__ w3,
                     float* __restrict__ Wp) {
    const float* w = blockIdx.y == 0 ? w0 : blockIdx.y == 1 ? w1 : blockIdx.y == 2 ? w2 : w3;
    float* out = Wp + (size_t)blockIdx.y * (256 * 1024);
    int o = blockIdx.x * 256 + threadIdx.x;   // o = k*1024 + j*4 + g
    int g = o & 3, j = (o >> 2) & 255, k = o >> 10;
    out[o] = w[(g * 256 + j) * 256 + k];
}

// ---------------- C[M,N] = A[M,K] @ W[N,K]^T + b1[N] + b2[N] ----------------
__global__ __launch_bounds__(256)
void gemm_bias_kernel(const float* __restrict__ A, const float* __restrict__ W,
                      const float* __restrict__ b1, const float* __restrict__ b2,
                      float* __restrict__ C, int M, int N, int K) {
    const int BK = 16;
    __shared__ float As[BK][128];
    __shared__ float Bs[BK][128];
    int tid = threadIdx.x;
    int bm = blockIdx.x * 128;
    int bn = blockIdx.y * 128;
    int tm = (tid >> 4) << 3;
    int tn = (tid & 15) << 3;
    int lr = tid >> 1;                 // tile row 0..127
    int lc = (tid & 1) << 3;           // col offset 0 or 8
    const float* Ap = A + (size_t)(bm + lr) * K + lc;
    const float* Wpt = W + (size_t)(bn + lr) * K + lc;
    float acc[8][8];
#pragma unroll
    for (int i = 0; i < 8; i++)
#pragma unroll
        for (int j = 0; j < 8; j++) acc[i][j] = 0.f;

    for (int k0 = 0; k0 < K; k0 += BK) {
        float4 a0 = *(const float4*)(Ap + k0);
        float4 a1 = *(const float4*)(Ap + k0 + 4);
        float4 w0 = *(const float4*)(Wpt + k0);
        float4 w1 = *(const float4*)(Wpt + k0 + 4);
        __syncthreads();
        As[lc+0][lr]=a0.x; As[lc+1][lr]=a0.y; As[lc+2][lr]=a0.z; As[lc+3][lr]=a0.w;
        As[lc+4][lr]=a1.x; As[lc+5][lr]=a1.y; As[lc+6][lr]=a1.z; As[lc+7][lr]=a1.w;
        Bs[lc+0][lr]=w0.x; Bs[lc+1][lr]=w0.y; Bs[lc+2][lr]=w0.z; Bs[lc+3][lr]=w0.w;
        Bs[lc+4][lr]=w1.x; Bs[lc+5][lr]=w1.y; Bs[lc+6][lr]=w1.z; Bs[lc+7][lr]=w1.w;
        __syncthreads();
#pragma unroll
        for (int k = 0; k < BK; k++) {
            float av[8], bv[8];
            *(float4*)&av[0] = *(const float4*)&As[k][tm];
            *(float4*)&av[4] = *(const float4*)&As[k][tm+4];
            *(float4*)&bv[0] = *(const float4*)&Bs[k][tn];
            *(float4*)&bv[4] = *(const float4*)&Bs[k][tn+4];
#pragma unroll
            for (int i = 0; i < 8; i++)
#pragma unroll
                for (int j = 0; j < 8; j++) acc[i][j] = fmaf(av[i], bv[j], acc[i][j]);
        }
    }
    float bj[8];
#pragma unroll
    for (int j = 0; j < 8; j++) bj[j] = b1[bn+tn+j] + b2[bn+tn+j];
#pragma unroll
    for (int i = 0; i < 8; i++) {
        float4 v0, v1;
        v0.x = acc[i][0]+bj[0]; v0.y = acc[i][1]+bj[1]; v0.z = acc[i][2]+bj[2]; v0.w = acc[i][3]+bj[3];
        v1.x = acc[i][4]+bj[4]; v1.y = acc[i][5]+bj[5]; v1.z = acc[i][6]+bj[6]; v1.w = acc[i][7]+bj[7];
        *(float4*)&C[(size_t)(bm+tm+i)*N + bn+tn]     = v0;
        *(float4*)&C[(size_t)(bm+tm+i)*N + bn+tn + 4] = v1;
    }
}

// ---------------- sequential LSTM scan, 2 sequences per block ----------------
// G: precomputed x@W_ih^T + b_ih + b_hh, layout [L*B][1024] (gate-major i,f,g,o)
// Wp: packed [k][j][4]. dir=0 fwd, dir=1 bwd (packed-sequence reversal per batch).
// xout: [L*B][512], writes cols dir*256..+255, zeroed at pads.
__global__ __launch_bounds__(256)
void lstm_scan_kernel(const float* __restrict__ Gf, const float* __restrict__ Gb,
                      const float* __restrict__ Wpf, const float* __restrict__ Wpb,
                      const int* __restrict__ lengths, float* __restrict__ xout) {
    int dir = blockIdx.x & 1;
    int b0 = (blockIdx.x >> 1) << 1;       // 2 batch elems per block
    const float* G = dir ? Gb : Gf;
    const float4* W4 = (const float4*)(dir ? Wpb : Wpf);
    int j = threadIdx.x;
    __shared__ float h2[256][2];
    h2[j][0] = 0.f; h2[j][1] = 0.f;
    __syncthreads();
    float c0 = 0.f, c1 = 0.f;
    int len0 = lengths[b0], len1 = lengths[b0+1];
    for (int s = 0; s < LSEQ; s++) {
        int t0 = dir ? (s < len0 ? len0-1-s : s) : s;
        int t1 = dir ? (s < len1 ? len1-1-s : s) : s;
        const float* g0 = G + (size_t)(t0*BB + b0) * 1024;
        const float* g1 = G + (size_t)(t1*BB + b0+1) * 1024;
        float a00=g0[j], a01=g0[256+j], a02=g0[512+j], a03=g0[768+j];
        float a10=g1[j], a11=g1[256+j], a12=g1[512+j], a13=g1[768+j];
#pragma unroll 8
        for (int k = 0; k < 256; k++) {
            float4 w = W4[(k << 8) + j];
            float2 hh = *(const float2*)&h2[k][0];
            a00 = fmaf(w.x, hh.x, a00); a01 = fmaf(w.y, hh.x, a01);
            a02 = fmaf(w.z, hh.x, a02); a03 = fmaf(w.w, hh.x, a03);
            a10 = fmaf(w.x, hh.y, a10); a11 = fmaf(w.y, hh.y, a11);
            a12 = fmaf(w.z, hh.y, a12); a13 = fmaf(w.w, hh.y, a13);
        }
        float i0 = 1.f/(1.f+expf(-a00)), f0 = 1.f/(1.f+expf(-a01));
        float gg0 = tanhf(a02),          o0 = 1.f/(1.f+expf(-a03));
        c0 = f0*c0 + i0*gg0;
        float h0n = o0 * tanhf(c0);
        float i1 = 1.f/(1.f+expf(-a10)), f1 = 1.f/(1.f+expf(-a11));
        float gg1 = tanhf(a12),          o1 = 1.f/(1.f+expf(-a13));
        c1 = f1*c1 + i1*gg1;
        float h1n = o1 * tanhf(c1);
        __syncthreads();
        h2[j][0] = h0n; h2[j][1] = h1n;
        xout[(size_t)(t0*BB + b0  )*512 + dir*256 + j] = (s < len0) ? h0n : 0.f;
        xout[(size_t)(t1*BB + b0+1)*512 + dir*256 + j] = (s < len1) ? h1n : 0.f;
        __syncthreads();
    }
}

// ---------------- emissions: em[r][n] = x[r]·w_out[n] + b_out[n] ----------------
__global__ __launch_bounds__(256)
void emis_kernel(const float* __restrict__ x, const float* __restrict__ w_out,
                 const float* __restrict__ b_out, float* __restrict__ em) {
    __shared__ float ws_[16][516];
    __shared__ float xs[16][516];
    int tid = threadIdx.x;
    size_t r0 = (size_t)blockIdx.x * 16;
    for (int i4 = tid; i4 < 2048; i4 += 256) {
        int r = i4 >> 7, k4 = (i4 & 127) << 2;
        *(float4*)&ws_[r][k4] = *(const float4*)&w_out[r*512 + k4];
        *(float4*)&xs[r][k4]  = *(const float4*)&x[(r0 + r)*512 + k4];
    }
    __syncthreads();
    int rr = tid >> 4, n = tid & 15;
    const float4* xr = (const float4*)&xs[rr][0];
    const float4* wr = (const float4*)&ws_[n][0];
    float4 s; s.x = s.y = s.z = s.w = 0.f;
#pragma unroll 8
    for (int k = 0; k < 128; k++) {
        float4 a = xr[k], b = wr[k];
        s.x = fmaf(a.x,b.x,s.x); s.y = fmaf(a.y,b.y,s.y);
        s.z = fmaf(a.z,b.z,s.z); s.w = fmaf(a.w,b.w,s.w);
    }
    em[(r0+rr)*16 + n] = s.x+s.y+s.z+s.w + b_out[n];
}

// ---------------- CRF Viterbi decode, one block per batch element ----------------
__global__ __launch_bounds__(64)
void viterbi_kernel(const float* __restrict__ em, const int* __restrict__ tokens,
                    const float* __restrict__ start_trans, const float* __restrict__ end_trans,
                    const float* __restrict__ trans, float* __restrict__ out) {
    __shared__ float em_s[256][16];
    __shared__ float tr_s[16][16];
    __shared__ float sc[16];
    __shared__ unsigned char hist[255][16];
    int b = blockIdx.x, tid = threadIdx.x;
    for (int i = tid; i < 4096; i += 64) {
        int t = i >> 4, n = i & 15;
        em_s[t][n] = em[(size_t)t*1024 + b*16 + n];
    }
    for (int i = tid; i < 256; i += 64) ((float*)tr_s)[i] = trans[i];
    __syncthreads();
    if (tid < 16) sc[tid] = start_trans[tid] + em_s[0][tid];
    __syncthreads();
    for (int t = 1; t < 256; t++) {
        float best = 0.f; int arg = 0;
        if (tid < 16) {
            best = sc[0] + tr_s[0][tid];
#pragma unroll
            for (int i = 1; i < 16; i++) {
                float v = sc[i] + tr_s[i][tid];
                if (v > best) { best = v; arg = i; }   // strict >: first-max, matches argmax
            }
            best += em_s[t][tid];
            hist[t-1][tid] = (unsigned char)arg;
        }
        bool m = tokens[t*64 + b] != 0;
        __syncthreads();
        if (tid < 16 && m) sc[tid] = best;
        __syncthreads();
    }
    if (tid == 0) {
        float best = sc[0] + end_trans[0]; int cur = 0;
        for (int jj = 1; jj < 16; jj++) {
            float v = sc[jj] + end_trans[jj];
            if (v > best) { best = v; cur = jj; }
        }
        out[b] = best;                               // best_score
        float* tags = out + 64;                      // tags [L][B] as float values
        tags[255*64 + b] = (tokens[255*64+b] != 0) ? (float)cur : 0.f;
        for (int t = 254; t >= 0; t--) {
            if (tokens[(t+1)*64 + b] != 0) cur = hist[t][cur];
            tags[t*64 + b] = (tokens[t*64+b] != 0) ? (float)cur : 0.f;
        }
    }
}

extern "C" void kernel_launch(void* const* d_in, const int* in_sizes, int n_in,
                              void* d_out, int out_size, void* d_ws, size_t ws_size,
                              hipStream_t stream) {
    const int*   tokens   = (const int*)d_in[0];
    const int*   lengths  = (const int*)d_in[1];
    const float* emb      = (const float*)d_in[2];
    const float* w_ih_l0f = (const float*)d_in[3];
    const float* w_hh_l0f = (const float*)d_in[4];
    const float* b_ih_l0f = (const float*)d_in[5];
    const float* b_hh_l0f = (const float*)d_in[6];
    const float* w_ih_l0b = (const float*)d_in[7];
    const float* w_hh_l0b = (const float*)d_in[8];
    const float* b_ih_l0b = (const float*)d_in[9];
    const float* b_hh_l0b = (const float*)d_in[10];
    const float* w_ih_l1f = (const float*)d_in[11];
    const float* w_hh_l1f = (const float*)d_in[12];
    const float* b_ih_l1f = (const float*)d_in[13];
    const float* b_hh_l1f = (const float*)d_in[14];
    const float* w_ih_l1b = (const float*)d_in[15];
    const float* w_hh_l1b = (const float*)d_in[16];
    const float* b_ih_l1b = (const float*)d_in[17];
    const float* b_hh_l1b = (const float*)d_in[18];
    const float* w_out    = (const float*)d_in[19];
    const float* b_out    = (const float*)d_in[20];
    const float* start_tr = (const float*)d_in[21];
    const float* end_tr   = (const float*)d_in[22];
    const float* trans    = (const float*)d_in[23];

    // workspace layout (floats): total 55,574,528 floats = 222.3 MB
    float* ws  = (float*)d_ws;
    float* x0  = ws;                       // [16384][256]
    float* x1  = x0 + 4194304;             // [16384][512]
    float* x2  = x1 + 8388608;             // [16384][512]
    float* Gf  = x2 + 8388608;             // [16384][1024]
    float* Gb  = Gf + 16777216;            // [16384][1024]
    float* Wp  = Gb + 16777216;            // 4 x [256*1024]
    float* Wp0f = Wp, *Wp0b = Wp + 262144, *Wp1f = Wp + 524288, *Wp1b = Wp + 786432;
    float* em  = x0;                       // reuse x0 (free after layer-0 GEMMs)

    embed_kernel<<<16384, 64, 0, stream>>>(tokens, emb, x0);
    pack_whh_kernel<<<dim3(1024, 4), 256, 0, stream>>>(w_hh_l0f, w_hh_l0b, w_hh_l1f, w_hh_l1b, Wp);

    dim3 gg(128, 8);
    gemm_bias_kernel<<<gg, 256, 0, stream>>>(x0, w_ih_l0f, b_ih_l0f, b_hh_l0f, Gf, 16384, 1024, 256);
    gemm_bias_kernel<<<gg, 256, 0, stream>>>(x0, w_ih_l0b, b_ih_l0b, b_hh_l0b, Gb, 16384, 1024, 256);
    lstm_scan_kernel<<<64, 256, 0, stream>>>(Gf, Gb, Wp0f, Wp0b, lengths, x1);

    gemm_bias_kernel<<<gg, 256, 0, stream>>>(x1, w_ih_l1f, b_ih_l1f, b_hh_l1f, Gf, 16384, 1024, 512);
    gemm_bias_kernel<<<gg, 256, 0, stream>>>(x1, w_ih_l1b, b_ih_l1b, b_hh_l1b, Gb, 16384, 1024, 512);
    lstm_scan_kernel<<<64, 256, 0, stream>>>(Gf, Gb, Wp1f, Wp1b, lengths, x2);

    emis_kernel<<<1024, 256, 0, stream>>>(x2, w_out, b_out, em);
    viterbi_kernel<<<64, 64, 0, stream>>>(em, tokens, start_tr, end_tr, trans, (float*)d_out);
}

// Round 2
// 4855.252 us; speedup vs baseline: 1.0011x; 1.0011x over previous
//
#include <hip/hip_runtime.h>
#include <hip/hip_bf16.h>
#include <math.h>

#define LSEQ 256
#define BB   64
#define EE   256
#define HH   256
#define TT   16

// ---------------- embedding gather: x0[r][e] = emb[tokens[r]][e] ----------------
__global__ __launch_bounds__(64)
void embed_kernel(const int* __restrict__ tokens, const float* __restrict__ emb,
                  float* __restrict__ x0) {
    int r = blockIdx.x;                       // r = t*B + b, 0..16383
    int tok = tokens[r];
    const float4* src = (const float4*)(emb + (size_t)tok * EE);
    float4* dst = (float4*)(x0 + (size_t)r * EE);
    dst[threadIdx.x] = src[threadIdx.x];      // 64 threads * float4 = 256 floats
}

// -------- transpose-pack W_hh: WpT[k][n] = w_hh[n][k]  (n = g*256+j gate-major) --------
__global__ __launch_bounds__(256)
void transpose_whh_kernel(const float* __restrict__ w0, const float* __restrict__ w1,
                          const float* __restrict__ w2, const float* __restrict__ w3,
                          float* __restrict__ WpT) {
    __shared__ float tile[64][65];
    const float* w = blockIdx.z == 0 ? w0 : blockIdx.z == 1 ? w1 : blockIdx.z == 2 ? w2 : w3;
    float* out = WpT + (size_t)blockIdx.z * 262144;
    int k0 = blockIdx.x * 64, n0 = blockIdx.y * 64, tid = threadIdx.x;
    for (int e = tid; e < 4096; e += 256) {
        int nl = e >> 6, kl = e & 63;                 // read in[n0+nl][k0+kl], lanes kl consecutive
        tile[nl][kl] = w[(size_t)(n0 + nl) * 256 + k0 + kl];
    }
    __syncthreads();
    for (int e = tid; e < 4096; e += 256) {
        int kl = e >> 6, nl = e & 63;                 // write out[k0+kl][n0+nl], lanes nl consecutive
        out[(size_t)(k0 + kl) * 1024 + n0 + nl] = tile[nl][kl];
    }
}

// ---------------- C[M,N] = A[M,K] @ W[N,K]^T + b1[N] + b2[N] ----------------
__global__ __launch_bounds__(256)
void gemm_bias_kernel(const float* __restrict__ A, const float* __restrict__ W,
                      const float* __restrict__ b1, const float* __restrict__ b2,
                      float* __restrict__ C, int M, int N, int K) {
    const int BK = 16;
    __shared__ float As[BK][128];
    __shared__ float Bs[BK][128];
    int tid = threadIdx.x;
    int bm = blockIdx.x * 128;
    int bn = blockIdx.y * 128;
    int tm = (tid >> 4) << 3;
    int tn = (tid & 15) << 3;
    int lr = tid >> 1;                 // tile row 0..127
    int lc = (tid & 1) << 3;           // col offset 0 or 8
    const float* Ap = A + (size_t)(bm + lr) * K + lc;
    const float* Wpt = W + (size_t)(bn + lr) * K + lc;
    float acc[8][8];
#pragma unroll
    for (int i = 0; i < 8; i++)
#pragma unroll
        for (int j = 0; j < 8; j++) acc[i][j] = 0.f;

    for (int k0 = 0; k0 < K; k0 += BK) {
        float4 a0 = *(const float4*)(Ap + k0);
        float4 a1 = *(const float4*)(Ap + k0 + 4);
        float4 w0 = *(const float4*)(Wpt + k0);
        float4 w1 = *(const float4*)(Wpt + k0 + 4);
        __syncthreads();
        As[lc+0][lr]=a0.x; As[lc+1][lr]=a0.y; As[lc+2][lr]=a0.z; As[lc+3][lr]=a0.w;
        As[lc+4][lr]=a1.x; As[lc+5][lr]=a1.y; As[lc+6][lr]=a1.z; As[lc+7][lr]=a1.w;
        Bs[lc+0][lr]=w0.x; Bs[lc+1][lr]=w0.y; Bs[lc+2][lr]=w0.z; Bs[lc+3][lr]=w0.w;
        Bs[lc+4][lr]=w1.x; Bs[lc+5][lr]=w1.y; Bs[lc+6][lr]=w1.z; Bs[lc+7][lr]=w1.w;
        __syncthreads();
#pragma unroll
        for (int k = 0; k < BK; k++) {
            float av[8], bv[8];
            *(float4*)&av[0] = *(const float4*)&As[k][tm];
            *(float4*)&av[4] = *(const float4*)&As[k][tm+4];
            *(float4*)&bv[0] = *(const float4*)&Bs[k][tn];
            *(float4*)&bv[4] = *(const float4*)&Bs[k][tn+4];
#pragma unroll
            for (int i = 0; i < 8; i++)
#pragma unroll
                for (int j = 0; j < 8; j++) acc[i][j] = fmaf(av[i], bv[j], acc[i][j]);
        }
    }
    float bj[8];
#pragma unroll
    for (int j = 0; j < 8; j++) bj[j] = b1[bn+tn+j] + b2[bn+tn+j];
#pragma unroll
    for (int i = 0; i < 8; i++) {
        float4 v0, v1;
        v0.x = acc[i][0]+bj[0]; v0.y = acc[i][1]+bj[1]; v0.z = acc[i][2]+bj[2]; v0.w = acc[i][3]+bj[3];
        v1.x = acc[i][4]+bj[4]; v1.y = acc[i][5]+bj[5]; v1.z = acc[i][6]+bj[6]; v1.w = acc[i][7]+bj[7];
        *(float4*)&C[(size_t)(bm+tm+i)*N + bn+tn]     = v0;
        *(float4*)&C[(size_t)(bm+tm+i)*N + bn+tn + 4] = v1;
    }
}

// ---------------- sequential LSTM scan, 2 sequences per block, 1024 threads ----------------
// G: precomputed x@W_ih^T + b_ih + b_hh, layout [L*B][1024] gate-major (i,f,g,o)
// WT: transposed W_hh [k][n] (n gate-major). dir=0 fwd, dir=1 bwd (packed-seq reversal).
// xout: [L*B][512], writes cols dir*256..+255, zeroed at pads.
// Thread roles: FMA phase: kq = tid>>8 (k-slice of 64), n4 = tid&255 (n-quad 4*n4..+3),
//               accumulates partials for both batches into LDS P[kq*2+b][n].
//               Combine phase (tid<512): b = tid>>8, j = tid&255: sum partials, gates, c/h.
__global__ __launch_bounds__(1024)
void lstm_scan_kernel(const float* __restrict__ Gf, const float* __restrict__ Gb,
                      const float* __restrict__ WTf, const float* __restrict__ WTb,
                      const int* __restrict__ lengths, float* __restrict__ xout) {
    int dir = blockIdx.x & 1;
    int b0  = (blockIdx.x >> 1) << 1;      // 2 batch elems per block
    const float*  G   = dir ? Gb : Gf;
    const float4* WT4 = (const float4*)(dir ? WTb : WTf);   // [k][256] float4 view

    __shared__ float h_lds[2][256];
    __shared__ float P[8][1024];           // [kq*2+b][n]

    int tid = threadIdx.x;
    int kq = tid >> 8;                     // 0..3
    int n4 = tid & 255;                    // n-quad index
    int cb = (tid >> 8) & 1;               // combine: batch 0/1 (valid for tid<512)
    int cj = tid & 255;                    // combine: hidden unit j

    int len0 = lengths[b0], len1 = lengths[b0 + 1];
    int mylen = cb ? len1 : len0;

    if (tid < 512) h_lds[cb][cj] = 0.f;
    __syncthreads();

    float c = 0.f;
    float gp0 = 0.f, gp1 = 0.f, gp2 = 0.f, gp3 = 0.f;
    if (tid < 512) {
        int t0 = dir ? (0 < mylen ? mylen - 1 : 0) : 0;
        const float* gr = G + (size_t)(t0 * BB + b0 + cb) * 1024;
        gp0 = gr[cj]; gp1 = gr[256 + cj]; gp2 = gr[512 + cj]; gp3 = gr[768 + cj];
    }

    const float4* wp = WT4 + (size_t)(kq * 64) * 256 + n4;   // row k, quad n4

    for (int s = 0; s < LSEQ; s++) {
        // ---- FMA phase: partial gates over this thread's 64-k slice, both batches ----
        float4 acc0 = {0.f, 0.f, 0.f, 0.f};
        float4 acc1 = {0.f, 0.f, 0.f, 0.f};
#pragma unroll 4
        for (int kk4 = 0; kk4 < 16; kk4++) {
            float4 h0 = *(const float4*)&h_lds[0][kq * 64 + kk4 * 4];   // uniform b128 broadcast
            float4 h1 = *(const float4*)&h_lds[1][kq * 64 + kk4 * 4];
#pragma unroll
            for (int r = 0; r < 4; r++) {
                float4 w = wp[(size_t)(kk4 * 4 + r) * 256];
                float hr0 = ((const float*)&h0)[r];
                float hr1 = ((const float*)&h1)[r];
                acc0.x = fmaf(w.x, hr0, acc0.x); acc0.y = fmaf(w.y, hr0, acc0.y);
                acc0.z = fmaf(w.z, hr0, acc0.z); acc0.w = fmaf(w.w, hr0, acc0.w);
                acc1.x = fmaf(w.x, hr1, acc1.x); acc1.y = fmaf(w.y, hr1, acc1.y);
                acc1.z = fmaf(w.z, hr1, acc1.z); acc1.w = fmaf(w.w, hr1, acc1.w);
            }
        }
        ((float4*)P)[(kq * 2 + 0) * 256 + n4] = acc0;
        ((float4*)P)[(kq * 2 + 1) * 256 + n4] = acc1;
        __syncthreads();

        // ---- combine phase: 512 threads (2 batches x 256 units) ----
        if (tid < 512) {
            int t = dir ? (s < mylen ? mylen - 1 - s : s) : s;
            float a0 = P[0+cb][cj]       + P[2+cb][cj]       + P[4+cb][cj]       + P[6+cb][cj]       + gp0;
            float a1 = P[0+cb][256+cj]   + P[2+cb][256+cj]   + P[4+cb][256+cj]   + P[6+cb][256+cj]   + gp1;
            float a2 = P[0+cb][512+cj]   + P[2+cb][512+cj]   + P[4+cb][512+cj]   + P[6+cb][512+cj]   + gp2;
            float a3 = P[0+cb][768+cj]   + P[2+cb][768+cj]   + P[4+cb][768+cj]   + P[6+cb][768+cj]   + gp3;
            float iv = 1.f / (1.f + expf(-a0));
            float fv = 1.f / (1.f + expf(-a1));
            float gv = tanhf(a2);
            float ov = 1.f / (1.f + expf(-a3));
            c = fv * c + iv * gv;
            float h = ov * tanhf(c);
            h_lds[cb][cj] = h;
            xout[(size_t)(t * BB + b0 + cb) * 512 + dir * 256 + cj] = (s < mylen) ? h : 0.f;
            // prefetch next step's G row (hidden under next FMA phase)
            int s2 = s + 1;
            if (s2 < LSEQ) {
                int t2 = dir ? (s2 < mylen ? mylen - 1 - s2 : s2) : s2;
                const float* gr = G + (size_t)(t2 * BB + b0 + cb) * 1024;
                gp0 = gr[cj]; gp1 = gr[256 + cj]; gp2 = gr[512 + cj]; gp3 = gr[768 + cj];
            }
        }
        __syncthreads();
    }
}

// ---------------- emissions: em[r][n] = x[r]·w_out[n] + b_out[n] ----------------
__global__ __launch_bounds__(256)
void emis_kernel(const float* __restrict__ x, const float* __restrict__ w_out,
                 const float* __restrict__ b_out, float* __restrict__ em) {
    __shared__ float ws_[16][516];
    __shared__ float xs[16][516];
    int tid = threadIdx.x;
    size_t r0 = (size_t)blockIdx.x * 16;
    for (int i4 = tid; i4 < 2048; i4 += 256) {
        int r = i4 >> 7, k4 = (i4 & 127) << 2;
        *(float4*)&ws_[r][k4] = *(const float4*)&w_out[r*512 + k4];
        *(float4*)&xs[r][k4]  = *(const float4*)&x[(r0 + r)*512 + k4];
    }
    __syncthreads();
    int rr = tid >> 4, n = tid & 15;
    const float4* xr = (const float4*)&xs[rr][0];
    const float4* wr = (const float4*)&ws_[n][0];
    float4 s; s.x = s.y = s.z = s.w = 0.f;
#pragma unroll 8
    for (int k = 0; k < 128; k++) {
        float4 a = xr[k], b = wr[k];
        s.x = fmaf(a.x,b.x,s.x); s.y = fmaf(a.y,b.y,s.y);
        s.z = fmaf(a.z,b.z,s.z); s.w = fmaf(a.w,b.w,s.w);
    }
    em[(r0+rr)*16 + n] = s.x+s.y+s.z+s.w + b_out[n];
}

// ---------------- CRF Viterbi decode, one block per batch element ----------------
__global__ __launch_bounds__(64)
void viterbi_kernel(const float* __restrict__ em, const int* __restrict__ tokens,
                    const float* __restrict__ start_trans, const float* __restrict__ end_trans,
                    const float* __restrict__ trans, float* __restrict__ out) {
    __shared__ float em_s[256][16];
    __shared__ float tr_s[16][16];
    __shared__ float sc[16];
    __shared__ unsigned char hist[255][16];
    int b = blockIdx.x, tid = threadIdx.x;
    for (int i = tid; i < 4096; i += 64) {
        int t = i >> 4, n = i & 15;
        em_s[t][n] = em[(size_t)t*1024 + b*16 + n];
    }
    for (int i = tid; i < 256; i += 64) ((float*)tr_s)[i] = trans[i];
    __syncthreads();
    if (tid < 16) sc[tid] = start_trans[tid] + em_s[0][tid];
    __syncthreads();
    for (int t = 1; t < 256; t++) {
        float best = 0.f; int arg = 0;
        if (tid < 16) {
            best = sc[0] + tr_s[0][tid];
#pragma unroll
            for (int i = 1; i < 16; i++) {
                float v = sc[i] + tr_s[i][tid];
                if (v > best) { best = v; arg = i; }   // strict >: first-max, matches argmax
            }
            best += em_s[t][tid];
            hist[t-1][tid] = (unsigned char)arg;
        }
        bool m = tokens[t*64 + b] != 0;
        __syncthreads();
        if (tid < 16 && m) sc[tid] = best;
        __syncthreads();
    }
    if (tid == 0) {
        float best = sc[0] + end_trans[0]; int cur = 0;
        for (int jj = 1; jj < 16; jj++) {
            float v = sc[jj] + end_trans[jj];
            if (v > best) { best = v; cur = jj; }
        }
        out[b] = best;                               // best_score
        float* tags = out + 64;                      // tags [L][B] as float values
        tags[255*64 + b] = (tokens[255*64+b] != 0) ? (float)cur : 0.f;
        for (int t = 254; t >= 0; t--) {
            if (tokens[(t+1)*64 + b] != 0) cur = hist[t][cur];
            tags[t*64 + b] = (tokens[t*64+b] != 0) ? (float)cur : 0.f;
        }
    }
}

extern "C" void kernel_launch(void* const* d_in, const int* in_sizes, int n_in,
                              void* d_out, int out_size, void* d_ws, size_t ws_size,
                              hipStream_t stream) {
    const int*   tokens   = (const int*)d_in[0];
    const int*   lengths  = (const int*)d_in[1];
    const float* emb      = (const float*)d_in[2];
    const float* w_ih_l0f = (const float*)d_in[3];
    const float* w_hh_l0f = (const float*)d_in[4];
    const float* b_ih_l0f = (const float*)d_in[5];
    const float* b_hh_l0f = (const float*)d_in[6];
    const float* w_ih_l0b = (const float*)d_in[7];
    const float* w_hh_l0b = (const float*)d_in[8];
    const float* b_ih_l0b = (const float*)d_in[9];
    const float* b_hh_l0b = (const float*)d_in[10];
    const float* w_ih_l1f = (const float*)d_in[11];
    const float* w_hh_l1f = (const float*)d_in[12];
    const float* b_ih_l1f = (const float*)d_in[13];
    const float* b_hh_l1f = (const float*)d_in[14];
    const float* w_ih_l1b = (const float*)d_in[15];
    const float* w_hh_l1b = (const float*)d_in[16];
    const float* b_ih_l1b = (const float*)d_in[17];
    const float* b_hh_l1b = (const float*)d_in[18];
    const float* w_out    = (const float*)d_in[19];
    const float* b_out    = (const float*)d_in[20];
    const float* start_tr = (const float*)d_in[21];
    const float* end_tr   = (const float*)d_in[22];
    const float* trans    = (const float*)d_in[23];

    // workspace layout (floats)
    float* ws  = (float*)d_ws;
    float* x0  = ws;                       // [16384][256]
    float* x1  = x0 + 4194304;             // [16384][512]
    float* x2  = x1 + 8388608;             // [16384][512]
    float* Gf  = x2 + 8388608;             // [16384][1024]
    float* Gb  = Gf + 16777216;            // [16384][1024]
    float* WpT = Gb + 16777216;            // 4 x [256][1024] transposed W_hh
    float* WT0f = WpT, *WT0b = WpT + 262144, *WT1f = WpT + 524288, *WT1b = WpT + 786432;
    float* em  = x0;                       // reuse x0 (free after layer-0 GEMMs)

    embed_kernel<<<16384, 64, 0, stream>>>(tokens, emb, x0);
    transpose_whh_kernel<<<dim3(4, 16, 4), 256, 0, stream>>>(w_hh_l0f, w_hh_l0b, w_hh_l1f, w_hh_l1b, WpT);

    dim3 gg(128, 8);
    gemm_bias_kernel<<<gg, 256, 0, stream>>>(x0, w_ih_l0f, b_ih_l0f, b_hh_l0f, Gf, 16384, 1024, 256);
    gemm_bias_kernel<<<gg, 256, 0, stream>>>(x0, w_ih_l0b, b_ih_l0b, b_hh_l0b, Gb, 16384, 1024, 256);
    lstm_scan_kernel<<<64, 1024, 0, stream>>>(Gf, Gb, WT0f, WT0b, lengths, x1);

    gemm_bias_kernel<<<gg, 256, 0, stream>>>(x1, w_ih_l1f, b_ih_l1f, b_hh_l1f, Gf, 16384, 1024, 512);
    gemm_bias_kernel<<<gg, 256, 0, stream>>>(x1, w_ih_l1b, b_ih_l1b, b_hh_l1b, Gb, 16384, 1024, 512);
    lstm_scan_kernel<<<64, 1024, 0, stream>>>(Gf, Gb, WT1f, WT1b, lengths, x2);

    emis_kernel<<<1024, 256, 0, stream>>>(x2, w_out, b_out, em);
    viterbi_kernel<<<64, 64, 0, stream>>>(em, tokens, start_tr, end_tr, trans, (float*)d_out);
}